// Round 12
// baseline (1997.314 us; speedup 1.0000x reference)
//
#include <hip/hip_runtime.h>
#include <math.h>

constexpr int HID  = 2048;
constexpr int NEXP = 128;
constexpr int TOPK = 8;
constexpr int BM   = 32;     // rows per block
constexpr int ROWS = 16384;
constexpr int BK   = 8;      // k chunk per iteration

typedef float f32x4 __attribute__((ext_vector_type(4)));

// f32 register-blocked router: no LDS in the main loop (round-6 PMC showed
// 7.5M bank conflicts + LDS-pipe oversubscription were the bottleneck).
// Thread = 1 row x 8 experts; W octet from global (L2-resident), X via L1
// broadcast (16 lanes share a row). Per-output fmaf runs k ascending ->
// logits bit-identical to the round-6 kernel that PASSED.
__global__ __launch_bounds__(512, 4)
void router_f32(const float* __restrict__ X, const float* __restrict__ W,
                float* __restrict__ out_w, float* __restrict__ out_i,
                float* __restrict__ out_l) {
    __shared__ float Ls[BM][NEXP + 4];   // 32 x 132 (epilogue only)

    const int tid = threadIdx.x;
    const int eq  = tid & 15;            // expert octet: experts eq*8 .. eq*8+7
    const int rg  = tid >> 4;            // row 0..31 within block
    const int row0 = blockIdx.x * BM;

    const float* __restrict__ xp = X + (size_t)(row0 + rg) * HID;
    const float* __restrict__ wp = W + (size_t)(eq * 8) * HID;

    float acc[8] = {};

    #pragma unroll 1
    for (int kc = 0; kc < HID; kc += BK) {
        const f32x4 x0 = *(const f32x4*)(xp + kc);
        const f32x4 x1 = *(const f32x4*)(xp + kc + 4);
        f32x4 w0[8], w1[8];
        #pragma unroll
        for (int e = 0; e < 8; ++e) {
            w0[e] = *(const f32x4*)(wp + (size_t)e * HID + kc);
            w1[e] = *(const f32x4*)(wp + (size_t)e * HID + kc + 4);
        }
        // k ascending per output (bit-identical accumulation order to round 6)
        #pragma unroll
        for (int kk = 0; kk < 4; ++kk)
            #pragma unroll
            for (int e = 0; e < 8; ++e)
                acc[e] = fmaf(x0[kk], w0[e][kk], acc[e]);
        #pragma unroll
        for (int kk = 0; kk < 4; ++kk)
            #pragma unroll
            for (int e = 0; e < 8; ++e)
                acc[e] = fmaf(x1[kk], w1[e][kk], acc[e]);
    }

    // stage logits for epilogue
    *(f32x4*)(&Ls[rg][eq * 8])     = *(const f32x4*)(&acc[0]);
    *(f32x4*)(&Ls[rg][eq * 8 + 4]) = *(const f32x4*)(&acc[4]);
    __syncthreads();

    // coalesced logits write: thread t -> row t>>4, cols (t&15)*8 .. +7
    {
        const int r = tid >> 4, q = tid & 15;
        const float* src = &Ls[r][q * 8];
        float* dst = out_l + (size_t)(row0 + r) * NEXP + q * 8;
        *(f32x4*)(dst)     = *(const f32x4*)(src);
        *(f32x4*)(dst + 4) = *(const f32x4*)(src + 4);
    }

    // top-8 + renormalized weights (proven in round 6): one lane per row
    if (tid < BM) {
        float v[TOPK];
        int   ixs[TOPK];
        #pragma unroll
        for (int j = 0; j < TOPK; ++j) { v[j] = -INFINITY; ixs[j] = 0; }
        const float* lr = &Ls[tid][0];
        #pragma unroll 1
        for (int cb = 0; cb < 32; ++cb) {
            f32x4 q4 = *(const f32x4*)(lr + cb * 4);
            #pragma unroll
            for (int u = 0; u < 4; ++u) {
                float s = q4[u];
                if (s > v[TOPK - 1]) {            // strict >: stable lower-index tie-break
                    v[TOPK - 1] = s; ixs[TOPK - 1] = cb * 4 + u;
                    #pragma unroll
                    for (int j = TOPK - 1; j > 0; --j)
                        if (v[j] > v[j - 1]) {
                            float tv = v[j]; v[j] = v[j - 1]; v[j - 1] = tv;
                            int   ti = ixs[j]; ixs[j] = ixs[j - 1]; ixs[j - 1] = ti;
                        }
                }
            }
        }
        const float m = v[0];
        float ex[TOPK], sum = 0.f;
        #pragma unroll
        for (int j = 0; j < TOPK; ++j) { ex[j] = expf(v[j] - m); sum += ex[j]; }
        const size_t grow = (size_t)(row0 + tid);
        #pragma unroll
        for (int j = 0; j < TOPK; ++j) {
            out_w[grow * TOPK + j] = ex[j] / sum;
            out_i[grow * TOPK + j] = (float)ixs[j];
        }
    }
}

extern "C" void kernel_launch(void* const* d_in, const int* in_sizes, int n_in,
                              void* d_out, int out_size, void* d_ws, size_t ws_size,
                              hipStream_t stream) {
    const float* X = (const float*)d_in[0];
    const float* W = (const float*)d_in[1];
    float* out   = (float*)d_out;
    float* out_w = out;                                 // [16384, 8]
    float* out_i = out + (size_t)ROWS * TOPK;           // [16384, 8] indices as float
    float* out_l = out + (size_t)ROWS * TOPK * 2;       // [16384, 128]

    dim3 grid(ROWS / BM);
    router_f32<<<grid, 512, 0, stream>>>(X, W, out_w, out_i, out_l);
}